// Round 4
// baseline (69.042 us; speedup 1.0000x reference)
//
#include <hip/hip_runtime.h>
#include <hip/hip_bf16.h>
#include <math.h>

typedef __bf16 bf16;
typedef __attribute__((ext_vector_type(8))) bf16 bf16x8;
typedef __attribute__((ext_vector_type(2))) bf16 bf16x2;
typedef __attribute__((ext_vector_type(16))) float f32x16;
typedef __attribute__((ext_vector_type(4))) unsigned int uint4v;

#define SQ 2048
#define DH 64
#define NH 16
#define QBLK 128
#define KVT 64
#define NKVT (SQ / KVT)
#define LOG2E 1.44269504088896340736f

// LDS: 3 buffers (prefetch distance 2); each buf = K [64][128B] @0 + Vt [64][128B] @8192
#define BUFSZ 16384
#define LDSV  8192

__device__ __forceinline__ int swz(int row, int colbyte) {
    return row * 128 + (colbyte ^ ((row & 7) << 4));
}

__device__ __forceinline__ float fast_exp2(float x) {
#if __has_builtin(__builtin_amdgcn_exp2f)
    return __builtin_amdgcn_exp2f(x);
#else
    return exp2f(x);
#endif
}

__device__ __forceinline__ unsigned pkbf16(float a, float b) {
    union { bf16x2 h; unsigned u; } x;
    x.h = (bf16x2){(bf16)a, (bf16)b};
    return x.u;
}

// permlane32_swap: a' = [a.lo | b.lo], b' = [a.hi | b.hi]
#if __has_builtin(__builtin_amdgcn_permlane32_swap)
__device__ __forceinline__ void plswap(unsigned &a, unsigned &b) {
    typedef __attribute__((ext_vector_type(2))) unsigned int uint2v;
    uint2v r = __builtin_amdgcn_permlane32_swap(a, b, false, false);
    a = r[0]; b = r[1];
}
#else
__device__ __forceinline__ void plswap(unsigned &a, unsigned &b) {
    asm volatile("v_permlane32_swap_b32 %0, %1" : "+v"(a), "+v"(b));
}
#endif

#if __has_builtin(__builtin_amdgcn_global_load_lds)
#define HAVE_GLL 1
__device__ __forceinline__ void async_copy16(const bf16* g, char* l) {
    __builtin_amdgcn_global_load_lds(
        (const __attribute__((address_space(1))) unsigned int*)g,
        (__attribute__((address_space(3))) unsigned int*)l, 16, 0, 0);
}
#else
#define HAVE_GLL 0
#endif

union FragU { uint4v u; bf16x8 b; };

// ---------- prepass: K fp32 -> bf16 row-major; V fp32 -> V^T bf16 ----------
__global__ __launch_bounds__(256)
void alibi_prep_kernel(const float* __restrict__ K, const float* __restrict__ V,
                       bf16* __restrict__ Kb, bf16* __restrict__ Vtb) {
    __shared__ bf16 lt[64][72];
    const int t  = threadIdx.x;
    const int s0 = blockIdx.x * 64;
    const int bh = blockIdx.y;
    if (blockIdx.z == 0) {
        const float* src = K + (size_t)bh * SQ * DH + (size_t)s0 * DH;
        bf16* dst = Kb + (size_t)bh * SQ * DH + (size_t)s0 * DH;
#pragma unroll
        for (int i = 0; i < 2; ++i) {
            int idx = t + 256 * i;
            int row = idx >> 3, c8 = idx & 7;
            const float* p = src + row * DH + c8 * 8;
            float4 a = *(const float4*)p, b = *(const float4*)(p + 4);
            bf16x8 pk = {(bf16)a.x,(bf16)a.y,(bf16)a.z,(bf16)a.w,
                         (bf16)b.x,(bf16)b.y,(bf16)b.z,(bf16)b.w};
            *(bf16x8*)(dst + row * DH + c8 * 8) = pk;
        }
    } else {
        const float* src = V + (size_t)bh * SQ * DH + (size_t)s0 * DH;
#pragma unroll
        for (int i = 0; i < 2; ++i) {
            int idx = t + 256 * i;
            int row = idx >> 3, c8 = idx & 7;
            const float* p = src + row * DH + c8 * 8;
            float4 a = *(const float4*)p, b = *(const float4*)(p + 4);
            bf16 e[8] = {(bf16)a.x,(bf16)a.y,(bf16)a.z,(bf16)a.w,
                         (bf16)b.x,(bf16)b.y,(bf16)b.z,(bf16)b.w};
#pragma unroll
            for (int j = 0; j < 8; ++j) lt[c8 * 8 + j][row] = e[j];
        }
        __syncthreads();
        bf16* dst = Vtb + (size_t)bh * DH * SQ;
#pragma unroll
        for (int i = 0; i < 2; ++i) {
            int idx = t + 256 * i;
            int d = idx >> 3, c8 = idx & 7;
            *(bf16x8*)(dst + (size_t)d * SQ + s0 + c8 * 8) = *(const bf16x8*)&lt[d][c8 * 8];
        }
    }
}

// ---------- main attention kernel ----------
__global__ __launch_bounds__(256)
void alibi_attn_kernel(const float* __restrict__ Q, const bf16* __restrict__ Kb,
                       const bf16* __restrict__ Vtb, float* __restrict__ Out) {
    __shared__ __align__(16) char lds[3 * BUFSZ];
    const int tid  = threadIdx.x;
    const int lane = tid & 63;
    const int wave = tid >> 6;
    const int r32  = lane & 31;
    const int hi   = lane >> 5;
    const int l8   = lane >> 3;

    // bijective XCD swizzle: each XCD gets 64 consecutive work ids = 4 bh
    const int lin = blockIdx.x + 16 * blockIdx.y;          // 0..511
    const int s   = (lin & 7) * 64 + (lin >> 3);
    const int qb  = s & 15;
    const int bh  = s >> 4;
    const int q0  = qb * QBLK;
    const int h   = bh & (NH - 1);
    const float SLOPE2N = -exp2f(-0.5f * (float)(h + 1)) * LOG2E;
    const float QSCALE  = 0.125f * LOG2E;

    const size_t base = (size_t)bh * SQ * DH;
    const float* Qp = Q + base;
    const bf16*  Kp = Kb + base;
    const bf16*  Vp = Vtb + base;          // [DH][SQ]
    float*       Op = Out + base;

    // Q B-frag (pre-scaled): lane holds Q[q=qrow][dstep*16 + hi*8 + j]
    const int qrow = q0 + wave * 32 + r32;
    bf16x8 qfrag[4];
#pragma unroll
    for (int dstep = 0; dstep < 4; ++dstep) {
        const float* sq = Qp + (size_t)qrow * DH + dstep * 16 + hi * 8;
        float4 a = *(const float4*)sq, b = *(const float4*)(sq + 4);
        qfrag[dstep] = (bf16x8){(bf16)(a.x*QSCALE),(bf16)(a.y*QSCALE),
                                (bf16)(a.z*QSCALE),(bf16)(a.w*QSCALE),
                                (bf16)(b.x*QSCALE),(bf16)(b.y*QSCALE),
                                (bf16)(b.z*QSCALE),(bf16)(b.w*QSCALE)};
    }

    f32x16 oacc[2];
#pragma unroll
    for (int d = 0; d < 2; ++d)
#pragma unroll
        for (int r = 0; r < 16; ++r) oacc[d][r] = 0.f;
    float ps0 = 0.f, ps1 = 0.f, ps2 = 0.f, ps3 = 0.f;
    const float qh = (float)(qrow - 4 * hi);

    const int cswz = ((lane & 7) << 4) ^ ((l8 & 7) << 4);   // pre-swizzled source chunk

    auto STAGE = [&](int bufi, int kvtile) {
        char* lb = lds + bufi * BUFSZ;
        const int kv0 = kvtile * KVT;
#pragma unroll
        for (int i = 0; i < 2; ++i) {
            const int chunk = wave * 2 + i;          // 0..7
            const int row = chunk * 8 + l8;
            const bf16* gK = Kp + (size_t)(kv0 + row) * DH + (cswz >> 1);
            const bf16* gV = Vp + (size_t)row * SQ + kv0 + (cswz >> 1);
#if HAVE_GLL
            async_copy16(gK, lb + chunk * 1024);
            async_copy16(gV, lb + LDSV + chunk * 1024);
#else
            *(bf16x8*)(lb + chunk * 1024 + lane * 16) = *(const bf16x8*)gK;
            *(bf16x8*)(lb + LDSV + chunk * 1024 + lane * 16) = *(const bf16x8*)gV;
#endif
        }
    };

    // prologue: prefetch tiles 0 and 1; wait only for tile 0 (4 oldest of 8)
    STAGE(0, 0);
    STAGE(1, 1);
    asm volatile("s_waitcnt vmcnt(4)" ::: "memory");
    __builtin_amdgcn_s_barrier();
    __builtin_amdgcn_sched_barrier(0);

    int cb = 0, sb = 2;    // compute-buffer, stage-buffer (prefetch distance 2)

    for (int t = 0; t < NKVT; ++t) {
        const int kv0 = t * KVT;
        const char* lb = lds + cb * BUFSZ;

        // ---- S^T = K·Q^T (32x32x16): lane holds S^T[k][q=qrow] ----
        f32x16 sacc[2];
        __builtin_amdgcn_s_setprio(1);
#pragma unroll
        for (int blk = 0; blk < 2; ++blk) {
            f32x16 acc;
#pragma unroll
            for (int r = 0; r < 16; ++r) acc[r] = 0.f;
#pragma unroll
            for (int dstep = 0; dstep < 4; ++dstep) {
                bf16x8 kf = *(const bf16x8*)(lb + swz(blk * 32 + r32, dstep * 32 + hi * 16));
                acc = __builtin_amdgcn_mfma_f32_32x32x16_bf16(kf, qfrag[dstep], acc, 0, 0, 0);
            }
            sacc[blk] = acc;
        }
        __builtin_amdgcn_s_setprio(0);

        // prefetch tile t+2 (wraps; keeps vmcnt discipline uniform)
        STAGE(sb, (t + 2) & (NKVT - 1));

        // ---- softmax, no max-tracking: p = exp2(s + bias) ----
        const float gq = qh - (float)kv0;
        float p[32];
#pragma unroll
        for (int blk = 0; blk < 2; ++blk)
#pragma unroll
            for (int reg = 0; reg < 16; ++reg) {
                const int krel = (reg & 3) + 8 * (reg >> 2) + 32 * blk;
                float d = gq - (float)krel;
                float s2 = fmaf(SLOPE2N, fabsf(d), sacc[blk][reg]);
                float e = fast_exp2(s2);
                p[blk * 16 + reg] = e;
                if ((reg & 3) == 0) ps0 += e;
                else if ((reg & 3) == 1) ps1 += e;
                else if ((reg & 3) == 2) ps2 += e;
                else ps3 += e;
            }

        // ---- PV: B-frag built in-register (cvt_pk + permlane32_swap) ----
        __builtin_amdgcn_s_setprio(1);
#pragma unroll
        for (int kstep = 0; kstep < 4; ++kstep) {
            const int b16 = (kstep >> 1) * 16;
            const int R = (kstep & 1) * 8;
            unsigned w0 = pkbf16(p[b16 + R + 0], p[b16 + R + 1]);
            unsigned w1 = pkbf16(p[b16 + R + 2], p[b16 + R + 3]);
            unsigned w2 = pkbf16(p[b16 + R + 4], p[b16 + R + 5]);
            unsigned w3 = pkbf16(p[b16 + R + 6], p[b16 + R + 7]);
            plswap(w0, w2);
            plswap(w1, w3);
            FragU pf; pf.u = (uint4v){w0, w1, w2, w3};
#pragma unroll
            for (int dblk = 0; dblk < 2; ++dblk) {
                bf16x8 vf = *(const bf16x8*)(lb + LDSV + swz(dblk * 32 + r32, kstep * 32 + hi * 16));
                oacc[dblk] = __builtin_amdgcn_mfma_f32_32x32x16_bf16(vf, pf.b, oacc[dblk], 0, 0, 0);
            }
        }
        __builtin_amdgcn_s_setprio(0);

        // ---- counted barrier: tile t+1's 4 loads (oldest) done; t+2's stay in flight ----
        asm volatile("s_waitcnt vmcnt(4)" ::: "memory");
        __builtin_amdgcn_s_barrier();
        __builtin_amdgcn_sched_barrier(0);

        cb = (cb == 2) ? 0 : cb + 1;
        sb = (sb == 2) ? 0 : sb + 1;
    }

    // ---- epilogue ----
    float psum = (ps0 + ps1) + (ps2 + ps3);
    psum += __shfl_xor(psum, 32);
    const float inv = 1.f / psum;
#pragma unroll
    for (int dblk = 0; dblk < 2; ++dblk)
#pragma unroll
        for (int g2 = 0; g2 < 4; ++g2) {
            float4 o = {oacc[dblk][4*g2+0] * inv, oacc[dblk][4*g2+1] * inv,
                        oacc[dblk][4*g2+2] * inv, oacc[dblk][4*g2+3] * inv};
            *(float4*)(Op + (size_t)qrow * DH + dblk * 32 + g2 * 8 + hi * 4) = o;
        }
}

extern "C" void kernel_launch(void* const* d_in, const int* in_sizes, int n_in,
                              void* d_out, int out_size, void* d_ws, size_t ws_size,
                              hipStream_t stream) {
    const float* q = (const float*)d_in[0];
    const float* k = (const float*)d_in[1];
    const float* v = (const float*)d_in[2];
    float* out = (float*)d_out;
    const int BH = in_sizes[0] / (SQ * DH);   // 32
    bf16* Kb  = (bf16*)d_ws;
    bf16* Vtb = (bf16*)((char*)d_ws + (size_t)BH * SQ * DH * sizeof(bf16));
    alibi_prep_kernel<<<dim3(SQ / 64, BH, 2), dim3(256), 0, stream>>>(k, v, Kb, Vtb);
    alibi_attn_kernel<<<dim3(SQ / QBLK, BH), dim3(256), 0, stream>>>(q, Kb, Vtb, out);
}

// Round 5
// 54.018 us; speedup vs baseline: 1.2781x; 1.2781x over previous
//
#include <hip/hip_runtime.h>
#include <hip/hip_bf16.h>
#include <math.h>

typedef __bf16 bf16;
typedef __attribute__((ext_vector_type(8))) bf16 bf16x8;
typedef __attribute__((ext_vector_type(2))) bf16 bf16x2;
typedef __attribute__((ext_vector_type(16))) float f32x16;
typedef __attribute__((ext_vector_type(4))) unsigned int uint4v;

#define SQ 2048
#define DH 64
#define NH 16
#define QBLK 128
#define KVT 64
#define NKVT (SQ / KVT)
#define LOG2E 1.44269504088896340736f

// LDS: 3 buffers (prefetch distance 2); each buf = K [64][128B] @0 + Vt [64][128B] @8192
#define BUFSZ 16384
#define LDSV  8192

__device__ __forceinline__ int swz(int row, int colbyte) {
    return row * 128 + (colbyte ^ ((row & 7) << 4));
}

__device__ __forceinline__ float fast_exp2(float x) {
#if __has_builtin(__builtin_amdgcn_exp2f)
    return __builtin_amdgcn_exp2f(x);
#else
    return exp2f(x);
#endif
}

__device__ __forceinline__ unsigned pkbf16(float a, float b) {
    union { bf16x2 h; unsigned u; } x;
    x.h = (bf16x2){(bf16)a, (bf16)b};
    return x.u;
}

// permlane32_swap: a' = [a.lo | b.lo], b' = [a.hi | b.hi]
#if __has_builtin(__builtin_amdgcn_permlane32_swap)
__device__ __forceinline__ void plswap(unsigned &a, unsigned &b) {
    typedef __attribute__((ext_vector_type(2))) unsigned int uint2v;
    uint2v r = __builtin_amdgcn_permlane32_swap(a, b, false, false);
    a = r[0]; b = r[1];
}
#else
__device__ __forceinline__ void plswap(unsigned &a, unsigned &b) {
    asm volatile("v_permlane32_swap_b32 %0, %1" : "+v"(a), "+v"(b));
}
#endif

#if __has_builtin(__builtin_amdgcn_global_load_lds)
#define HAVE_GLL 1
__device__ __forceinline__ void async_copy16(const bf16* g, char* l) {
    __builtin_amdgcn_global_load_lds(
        (const __attribute__((address_space(1))) unsigned int*)g,
        (__attribute__((address_space(3))) unsigned int*)l, 16, 0, 0);
}
#else
#define HAVE_GLL 0
#endif

union FragU { uint4v u; bf16x8 b; };

// ---------- prepass: K fp32 -> bf16 row-major; V fp32 -> V^T bf16 ----------
__global__ __launch_bounds__(256)
void alibi_prep_kernel(const float* __restrict__ K, const float* __restrict__ V,
                       bf16* __restrict__ Kb, bf16* __restrict__ Vtb) {
    __shared__ bf16 lt[64][72];
    const int t  = threadIdx.x;
    const int s0 = blockIdx.x * 64;
    const int bh = blockIdx.y;
    if (blockIdx.z == 0) {
        const float* src = K + (size_t)bh * SQ * DH + (size_t)s0 * DH;
        bf16* dst = Kb + (size_t)bh * SQ * DH + (size_t)s0 * DH;
#pragma unroll
        for (int i = 0; i < 2; ++i) {
            int idx = t + 256 * i;
            int row = idx >> 3, c8 = idx & 7;
            const float* p = src + row * DH + c8 * 8;
            float4 a = *(const float4*)p, b = *(const float4*)(p + 4);
            bf16x8 pk = {(bf16)a.x,(bf16)a.y,(bf16)a.z,(bf16)a.w,
                         (bf16)b.x,(bf16)b.y,(bf16)b.z,(bf16)b.w};
            *(bf16x8*)(dst + row * DH + c8 * 8) = pk;
        }
    } else {
        const float* src = V + (size_t)bh * SQ * DH + (size_t)s0 * DH;
#pragma unroll
        for (int i = 0; i < 2; ++i) {
            int idx = t + 256 * i;
            int row = idx >> 3, c8 = idx & 7;
            const float* p = src + row * DH + c8 * 8;
            float4 a = *(const float4*)p, b = *(const float4*)(p + 4);
            bf16 e[8] = {(bf16)a.x,(bf16)a.y,(bf16)a.z,(bf16)a.w,
                         (bf16)b.x,(bf16)b.y,(bf16)b.z,(bf16)b.w};
#pragma unroll
            for (int j = 0; j < 8; ++j) lt[c8 * 8 + j][row] = e[j];
        }
        __syncthreads();
        bf16* dst = Vtb + (size_t)bh * DH * SQ;
#pragma unroll
        for (int i = 0; i < 2; ++i) {
            int idx = t + 256 * i;
            int d = idx >> 3, c8 = idx & 7;
            *(bf16x8*)(dst + (size_t)d * SQ + s0 + c8 * 8) = *(const bf16x8*)&lt[d][c8 * 8];
        }
    }
}

// ---------- main attention kernel (banded) ----------
__global__ __launch_bounds__(256)
void alibi_attn_kernel(const float* __restrict__ Q, const bf16* __restrict__ Kb,
                       const bf16* __restrict__ Vtb, float* __restrict__ Out) {
    __shared__ __align__(16) char lds[3 * BUFSZ];
    const int tid  = threadIdx.x;
    const int lane = tid & 63;
    const int wave = tid >> 6;
    const int r32  = lane & 31;
    const int hi   = lane >> 5;
    const int l8   = lane >> 3;

    // ---- work mapping: rank = heavy-first order; blocks b and b+256 share a CU
    //      under round-robin dispatch -> pair (heavy, light) per CU ----
    const int b   = blockIdx.x;                 // 0..511
    const int r   = (b < 256) ? b : 767 - b;    // rank 0..511, tiles desc
    const int h   = 15 - (r >> 5);              // rank group -> head (band width desc)
    const int sub = r & 31;
    const int bh  = (sub >> 4) * NH + h;        // batch = sub>>4
    const int q0  = (sub & 15) * QBLK;

    const float slope2  = exp2f(-0.5f * (float)(h + 1)) * LOG2E;
    const float SLOPE2N = -slope2;
    const float QSCALE  = 0.125f * LOG2E;

    // ---- ALiBi band: drop tiles with slope2*minDelta > 24 (rel err < 1e-5) ----
    const int D = (int)(24.0f / slope2);
    const int a0 = q0 - D;
    const int tmin = (a0 <= 0) ? 0 : (a0 >> 6);
    const int tmax = min(NKVT - 1, (q0 + QBLK - 1 + D) >> 6);

    const size_t base = (size_t)bh * SQ * DH;
    const float* Qp = Q + base;
    const bf16*  Kp = Kb + base;
    const bf16*  Vp = Vtb + base;          // [DH][SQ]
    float*       Op = Out + base;

    // Q B-frag (pre-scaled): lane holds Q[q=qrow][dstep*16 + hi*8 + j]
    const int qrow = q0 + wave * 32 + r32;
    bf16x8 qfrag[4];
#pragma unroll
    for (int dstep = 0; dstep < 4; ++dstep) {
        const float* sq = Qp + (size_t)qrow * DH + dstep * 16 + hi * 8;
        float4 a = *(const float4*)sq, bb = *(const float4*)(sq + 4);
        qfrag[dstep] = (bf16x8){(bf16)(a.x*QSCALE),(bf16)(a.y*QSCALE),
                                (bf16)(a.z*QSCALE),(bf16)(a.w*QSCALE),
                                (bf16)(bb.x*QSCALE),(bf16)(bb.y*QSCALE),
                                (bf16)(bb.z*QSCALE),(bf16)(bb.w*QSCALE)};
    }

    f32x16 oacc[2];
#pragma unroll
    for (int d = 0; d < 2; ++d)
#pragma unroll
        for (int rr = 0; rr < 16; ++rr) oacc[d][rr] = 0.f;
    float ps0 = 0.f, ps1 = 0.f, ps2 = 0.f, ps3 = 0.f;
    const float qh = (float)(qrow - 4 * hi);

    const int cswz = ((lane & 7) << 4) ^ ((l8 & 7) << 4);   // pre-swizzled source chunk

    auto STAGE = [&](int bufi, int kvtile) {
        char* lb = lds + bufi * BUFSZ;
        const int kv0 = kvtile * KVT;
#pragma unroll
        for (int i = 0; i < 2; ++i) {
            const int chunk = wave * 2 + i;          // 0..7
            const int row = chunk * 8 + l8;
            const bf16* gK = Kp + (size_t)(kv0 + row) * DH + (cswz >> 1);
            const bf16* gV = Vp + (size_t)row * SQ + kv0 + (cswz >> 1);
#if HAVE_GLL
            async_copy16(gK, lb + chunk * 1024);
            async_copy16(gV, lb + LDSV + chunk * 1024);
#else
            *(bf16x8*)(lb + chunk * 1024 + lane * 16) = *(const bf16x8*)gK;
            *(bf16x8*)(lb + LDSV + chunk * 1024 + lane * 16) = *(const bf16x8*)gV;
#endif
        }
    };

    // prologue: prefetch first two band tiles (band always has >= 3 tiles)
    STAGE(0, tmin);
    STAGE(1, tmin + 1);
    asm volatile("s_waitcnt vmcnt(4)" ::: "memory");
    __builtin_amdgcn_s_barrier();
    __builtin_amdgcn_sched_barrier(0);

    int cb = 0, sb = 2;    // compute-buffer, stage-buffer (prefetch distance 2)

    for (int t = tmin; t <= tmax; ++t) {
        const int kv0 = t * KVT;
        const char* lb = lds + cb * BUFSZ;

        // ---- S^T = K·Q^T (32x32x16): lane holds S^T[k][q=qrow] ----
        f32x16 sacc[2];
        __builtin_amdgcn_s_setprio(1);
#pragma unroll
        for (int blk = 0; blk < 2; ++blk) {
            f32x16 acc;
#pragma unroll
            for (int rr = 0; rr < 16; ++rr) acc[rr] = 0.f;
#pragma unroll
            for (int dstep = 0; dstep < 4; ++dstep) {
                bf16x8 kf = *(const bf16x8*)(lb + swz(blk * 32 + r32, dstep * 32 + hi * 16));
                acc = __builtin_amdgcn_mfma_f32_32x32x16_bf16(kf, qfrag[dstep], acc, 0, 0, 0);
            }
            sacc[blk] = acc;
        }
        __builtin_amdgcn_s_setprio(0);

        // prefetch tile t+2 (clamped; keeps vmcnt discipline uniform)
        STAGE(sb, min(t + 2, tmax));

        // ---- softmax, no max-tracking: p = exp2(s + bias) ----
        const float gq = qh - (float)kv0;
        float p[32];
#pragma unroll
        for (int blk = 0; blk < 2; ++blk)
#pragma unroll
            for (int reg = 0; reg < 16; ++reg) {
                const int krel = (reg & 3) + 8 * (reg >> 2) + 32 * blk;
                float d = gq - (float)krel;
                float s2 = fmaf(SLOPE2N, fabsf(d), sacc[blk][reg]);
                float e = fast_exp2(s2);
                p[blk * 16 + reg] = e;
                if ((reg & 3) == 0) ps0 += e;
                else if ((reg & 3) == 1) ps1 += e;
                else if ((reg & 3) == 2) ps2 += e;
                else ps3 += e;
            }

        // ---- PV: B-frag built in-register (cvt_pk + permlane32_swap) ----
        __builtin_amdgcn_s_setprio(1);
#pragma unroll
        for (int kstep = 0; kstep < 4; ++kstep) {
            const int b16 = (kstep >> 1) * 16;
            const int R = (kstep & 1) * 8;
            unsigned w0 = pkbf16(p[b16 + R + 0], p[b16 + R + 1]);
            unsigned w1 = pkbf16(p[b16 + R + 2], p[b16 + R + 3]);
            unsigned w2 = pkbf16(p[b16 + R + 4], p[b16 + R + 5]);
            unsigned w3 = pkbf16(p[b16 + R + 6], p[b16 + R + 7]);
            plswap(w0, w2);
            plswap(w1, w3);
            FragU pf; pf.u = (uint4v){w0, w1, w2, w3};
#pragma unroll
            for (int dblk = 0; dblk < 2; ++dblk) {
                bf16x8 vf = *(const bf16x8*)(lb + LDSV + swz(dblk * 32 + r32, kstep * 32 + hi * 16));
                oacc[dblk] = __builtin_amdgcn_mfma_f32_32x32x16_bf16(vf, pf.b, oacc[dblk], 0, 0, 0);
            }
        }
        __builtin_amdgcn_s_setprio(0);

        // ---- counted barrier: next tile's 4 loads (oldest) done; +2's in flight ----
        asm volatile("s_waitcnt vmcnt(4)" ::: "memory");
        __builtin_amdgcn_s_barrier();
        __builtin_amdgcn_sched_barrier(0);

        cb = (cb == 2) ? 0 : cb + 1;
        sb = (sb == 2) ? 0 : sb + 1;
    }

    // ---- epilogue ----
    float psum = (ps0 + ps1) + (ps2 + ps3);
    psum += __shfl_xor(psum, 32);
    const float inv = 1.f / psum;
#pragma unroll
    for (int dblk = 0; dblk < 2; ++dblk)
#pragma unroll
        for (int g2 = 0; g2 < 4; ++g2) {
            float4 o = {oacc[dblk][4*g2+0] * inv, oacc[dblk][4*g2+1] * inv,
                        oacc[dblk][4*g2+2] * inv, oacc[dblk][4*g2+3] * inv};
            *(float4*)(Op + (size_t)qrow * DH + dblk * 32 + g2 * 8 + hi * 4) = o;
        }
}

extern "C" void kernel_launch(void* const* d_in, const int* in_sizes, int n_in,
                              void* d_out, int out_size, void* d_ws, size_t ws_size,
                              hipStream_t stream) {
    const float* q = (const float*)d_in[0];
    const float* k = (const float*)d_in[1];
    const float* v = (const float*)d_in[2];
    float* out = (float*)d_out;
    const int BH = in_sizes[0] / (SQ * DH);   // 32
    bf16* Kb  = (bf16*)d_ws;
    bf16* Vtb = (bf16*)((char*)d_ws + (size_t)BH * SQ * DH * sizeof(bf16));
    alibi_prep_kernel<<<dim3(SQ / 64, BH, 2), dim3(256), 0, stream>>>(k, v, Kb, Vtb);
    alibi_attn_kernel<<<dim3(512), dim3(256), 0, stream>>>(q, Kb, Vtb, out);
}

// Round 7
// 49.669 us; speedup vs baseline: 1.3900x; 1.0876x over previous
//
#include <hip/hip_runtime.h>
#include <hip/hip_bf16.h>
#include <math.h>

typedef __bf16 bf16;
typedef __attribute__((ext_vector_type(8))) bf16 bf16x8;
typedef __attribute__((ext_vector_type(2))) bf16 bf16x2;
typedef __attribute__((ext_vector_type(16))) float f32x16;
typedef __attribute__((ext_vector_type(4))) unsigned int uint4v;

#define SQ 2048
#define DH 64
#define NH 16
#define QBLK 64
#define KVT 64
#define NKVT (SQ / KVT)
#define LOG2E 1.44269504088896340736f

// LDS: 2 parity buffers; each = K [64][128B] @0 + Vt [64][128B] @8192 (16 KB)
// epilogue reuses the same 32 KB for partial-O exchange.
#define PBUF  16384
#define LDSV  8192
#define LDS_BYTES 32768

__device__ __forceinline__ int swz(int row, int colbyte) {
    return row * 128 + (colbyte ^ ((row & 7) << 4));
}

__device__ __forceinline__ float fast_exp2(float x) {
#if __has_builtin(__builtin_amdgcn_exp2f)
    return __builtin_amdgcn_exp2f(x);
#else
    return exp2f(x);
#endif
}

__device__ __forceinline__ unsigned pkbf16(float a, float b) {
    union { bf16x2 h; unsigned u; } x;
    x.h = (bf16x2){(bf16)a, (bf16)b};
    return x.u;
}

// permlane32_swap: a' = [a.lo | b.lo], b' = [a.hi | b.hi]
#if __has_builtin(__builtin_amdgcn_permlane32_swap)
__device__ __forceinline__ void plswap(unsigned &a, unsigned &b) {
    typedef __attribute__((ext_vector_type(2))) unsigned int uint2v;
    uint2v r = __builtin_amdgcn_permlane32_swap(a, b, false, false);
    a = r[0]; b = r[1];
}
#else
__device__ __forceinline__ void plswap(unsigned &a, unsigned &b) {
    asm volatile("v_permlane32_swap_b32 %0, %1" : "+v"(a), "+v"(b));
}
#endif

#if __has_builtin(__builtin_amdgcn_global_load_lds)
#define HAVE_GLL 1
__device__ __forceinline__ void async_copy16(const bf16* g, char* l) {
    __builtin_amdgcn_global_load_lds(
        (const __attribute__((address_space(1))) unsigned int*)g,
        (__attribute__((address_space(3))) unsigned int*)l, 16, 0, 0);
}
#else
#define HAVE_GLL 0
#endif

union FragU { uint4v u; bf16x8 b; };

// ---------- prepass: K fp32 -> bf16 row-major; V fp32 -> V^T bf16 ----------
__global__ __launch_bounds__(256)
void alibi_prep_kernel(const float* __restrict__ K, const float* __restrict__ V,
                       bf16* __restrict__ Kb, bf16* __restrict__ Vtb) {
    __shared__ bf16 lt[64][72];
    const int t  = threadIdx.x;
    const int s0 = blockIdx.x * 64;
    const int bh = blockIdx.y;
    if (blockIdx.z == 0) {
        const float* src = K + (size_t)bh * SQ * DH + (size_t)s0 * DH;
        bf16* dst = Kb + (size_t)bh * SQ * DH + (size_t)s0 * DH;
#pragma unroll
        for (int i = 0; i < 2; ++i) {
            int idx = t + 256 * i;
            int row = idx >> 3, c8 = idx & 7;
            const float* p = src + row * DH + c8 * 8;
            float4 a = *(const float4*)p, b = *(const float4*)(p + 4);
            bf16x8 pk = {(bf16)a.x,(bf16)a.y,(bf16)a.z,(bf16)a.w,
                         (bf16)b.x,(bf16)b.y,(bf16)b.z,(bf16)b.w};
            *(bf16x8*)(dst + row * DH + c8 * 8) = pk;
        }
    } else {
        const float* src = V + (size_t)bh * SQ * DH + (size_t)s0 * DH;
#pragma unroll
        for (int i = 0; i < 2; ++i) {
            int idx = t + 256 * i;
            int row = idx >> 3, c8 = idx & 7;
            const float* p = src + row * DH + c8 * 8;
            float4 a = *(const float4*)p, b = *(const float4*)(p + 4);
            bf16 e[8] = {(bf16)a.x,(bf16)a.y,(bf16)a.z,(bf16)a.w,
                         (bf16)b.x,(bf16)b.y,(bf16)b.z,(bf16)b.w};
#pragma unroll
            for (int j = 0; j < 8; ++j) lt[c8 * 8 + j][row] = e[j];
        }
        __syncthreads();
        bf16* dst = Vtb + (size_t)bh * DH * SQ;
#pragma unroll
        for (int i = 0; i < 2; ++i) {
            int idx = t + 256 * i;
            int d = idx >> 3, c8 = idx & 7;
            *(bf16x8*)(dst + (size_t)d * SQ + s0 + c8 * 8) = *(const bf16x8*)&lt[d][c8 * 8];
        }
    }
}

// ---------- main attention kernel (banded, KV-parallel waves) ----------
__global__ __launch_bounds__(256, 4)
void alibi_attn_kernel(const float* __restrict__ Q, const bf16* __restrict__ Kb,
                       const bf16* __restrict__ Vtb, float* __restrict__ Out) {
    __shared__ __align__(16) char lds[LDS_BYTES];
    const int tid   = threadIdx.x;
    const int lane  = tid & 63;
    const int wave  = tid >> 6;
    const int par   = wave >> 1;    // KV parity this wave computes
    const int kind  = wave & 1;     // staging role: 0 = K, 1 = Vt
    const int qhalf = wave & 1;     // q-half this wave computes
    const int r32   = lane & 31;
    const int hi    = lane >> 5;
    const int l8    = lane >> 3;

    // ---- heavy-first quartet mapping: blocks {i, 256+i, 512+i, 768+i} share a CU
    //      (round-robin heuristic; speed-only) and get ranks {i, 511-i, 512+i, 1023-i} ----
    const int b  = blockIdx.x;           // 0..1023
    const int qd = b >> 8, i = b & 255;
    int r;
    if      (qd == 0) r = i;
    else if (qd == 1) r = 511 - i;
    else if (qd == 2) r = 512 + i;
    else              r = 1023 - i;
    const int h   = 15 - (r >> 6);       // 64 ranks per head, widest bands first
    const int sub = r & 63;
    const int bh  = (sub >> 5) * NH + h; // batch = sub>>5
    const int q0  = (sub & 31) * QBLK;

    const float slope2  = exp2f(-0.5f * (float)(h + 1)) * LOG2E;
    const float SLOPE2N = -slope2;
    const float QSCALE  = 0.125f * LOG2E;

    // ---- ALiBi band: drop tiles with slope2*minDelta > 24 (rel err < 1e-5) ----
    const int D = (int)(24.0f / slope2);
    const int a0 = q0 - D;
    const int tmin = (a0 <= 0) ? 0 : (a0 >> 6);
    const int tmax = min(NKVT - 1, (q0 + QBLK - 1 + D) >> 6);
    const int nsteps = ((tmax - tmin + 1) + 1) >> 1;

    const size_t base = (size_t)bh * SQ * DH;
    const float* Qp = Q + base;
    const bf16*  Kp = Kb + base;
    const bf16*  Vp = Vtb + base;        // [DH][SQ]
    float*       Op = Out + base;

    // Q B-frag (pre-scaled): lane holds Q[q=qrow][dstep*16 + hi*8 + j]
    const int qrow = q0 + qhalf * 32 + r32;
    bf16x8 qfrag[4];
#pragma unroll
    for (int dstep = 0; dstep < 4; ++dstep) {
        const float* sq = Qp + (size_t)qrow * DH + dstep * 16 + hi * 8;
        float4 a = *(const float4*)sq, bb = *(const float4*)(sq + 4);
        qfrag[dstep] = (bf16x8){(bf16)(a.x*QSCALE),(bf16)(a.y*QSCALE),
                                (bf16)(a.z*QSCALE),(bf16)(a.w*QSCALE),
                                (bf16)(bb.x*QSCALE),(bf16)(bb.y*QSCALE),
                                (bf16)(bb.z*QSCALE),(bf16)(bb.w*QSCALE)};
    }

    f32x16 oacc[2];
#pragma unroll
    for (int d = 0; d < 2; ++d)
#pragma unroll
        for (int rr = 0; rr < 16; ++rr) oacc[d][rr] = 0.f;
    float ps0 = 0.f, ps1 = 0.f, ps2 = 0.f, ps3 = 0.f;
    const float qh = (float)(qrow - 4 * hi);

    const int cswz = ((lane & 7) << 4) ^ (l8 << 4);      // pre-swizzled source chunk
    char* const sbuf = lds + par * PBUF + kind * LDSV;   // my staging section
    const char* const cbuf = lds + par * PBUF;           // my compute buffer

    for (int s = 0; s < nsteps; ++s) {
        const int tc = tmin + 2 * s + par;        // my compute tile
        const int ts = min(tc, tmax);             // staged tile (clamped dup ok)

        // ---- stage my section: 8 chunks of 1 KB ----
        {
            const int kv0s = ts * KVT;
            if (kind == 0) {
#pragma unroll
                for (int c = 0; c < 8; ++c) {
                    const int row = c * 8 + l8;
                    const bf16* gK = Kp + (size_t)(kv0s + row) * DH + (cswz >> 1);
#if HAVE_GLL
                    async_copy16(gK, sbuf + c * 1024);
#else
                    *(bf16x8*)(sbuf + c * 1024 + lane * 16) = *(const bf16x8*)gK;
#endif
                }
            } else {
#pragma unroll
                for (int c = 0; c < 8; ++c) {
                    const int row = c * 8 + l8;
                    const bf16* gV = Vp + (size_t)row * SQ + kv0s + (cswz >> 1);
#if HAVE_GLL
                    async_copy16(gV, sbuf + c * 1024);
#else
                    *(bf16x8*)(sbuf + c * 1024 + lane * 16) = *(const bf16x8*)gV;
#endif
                }
            }
        }
        asm volatile("s_waitcnt vmcnt(0)" ::: "memory");
        __builtin_amdgcn_s_barrier();
        __builtin_amdgcn_sched_barrier(0);

        if (tc <= tmax) {
            const int kv0 = tc * KVT;

            // ---- S^T = K·Q^T (32x32x16): lane holds S^T[k][q=qrow] ----
            f32x16 sacc[2];
            __builtin_amdgcn_s_setprio(1);
#pragma unroll
            for (int blk = 0; blk < 2; ++blk) {
                f32x16 acc;
#pragma unroll
                for (int rr = 0; rr < 16; ++rr) acc[rr] = 0.f;
#pragma unroll
                for (int dstep = 0; dstep < 4; ++dstep) {
                    bf16x8 kf = *(const bf16x8*)(cbuf + swz(blk * 32 + r32, dstep * 32 + hi * 16));
                    acc = __builtin_amdgcn_mfma_f32_32x32x16_bf16(kf, qfrag[dstep], acc, 0, 0, 0);
                }
                sacc[blk] = acc;
            }
            __builtin_amdgcn_s_setprio(0);

            // ---- softmax, no max-tracking: p = exp2(s + bias) ----
            const float gq = qh - (float)kv0;
            float p[32];
#pragma unroll
            for (int blk = 0; blk < 2; ++blk)
#pragma unroll
                for (int reg = 0; reg < 16; ++reg) {
                    const int krel = (reg & 3) + 8 * (reg >> 2) + 32 * blk;
                    float d = gq - (float)krel;
                    float s2 = fmaf(SLOPE2N, fabsf(d), sacc[blk][reg]);
                    float e = fast_exp2(s2);
                    p[blk * 16 + reg] = e;
                    if ((reg & 3) == 0) ps0 += e;
                    else if ((reg & 3) == 1) ps1 += e;
                    else if ((reg & 3) == 2) ps2 += e;
                    else ps3 += e;
                }

            // ---- PV: B-frag built in-register (cvt_pk + permlane32_swap) ----
            __builtin_amdgcn_s_setprio(1);
#pragma unroll
            for (int kstep = 0; kstep < 4; ++kstep) {
                const int b16 = (kstep >> 1) * 16;
                const int R = (kstep & 1) * 8;
                unsigned w0 = pkbf16(p[b16 + R + 0], p[b16 + R + 1]);
                unsigned w1 = pkbf16(p[b16 + R + 2], p[b16 + R + 3]);
                unsigned w2 = pkbf16(p[b16 + R + 4], p[b16 + R + 5]);
                unsigned w3 = pkbf16(p[b16 + R + 6], p[b16 + R + 7]);
                plswap(w0, w2);
                plswap(w1, w3);
                FragU pf; pf.u = (uint4v){w0, w1, w2, w3};
#pragma unroll
                for (int dblk = 0; dblk < 2; ++dblk) {
                    bf16x8 vf = *(const bf16x8*)(cbuf + LDSV + swz(dblk * 32 + r32, kstep * 32 + hi * 16));
                    oacc[dblk] = __builtin_amdgcn_mfma_f32_32x32x16_bf16(vf, pf.b, oacc[dblk], 0, 0, 0);
                }
            }
            __builtin_amdgcn_s_setprio(0);
        }
        __builtin_amdgcn_s_barrier();
        __builtin_amdgcn_sched_barrier(0);
    }

    // ---- combine parities: waves 2,3 hand (oacc, psum) to waves 0,1 via LDS ----
    float psum = (ps0 + ps1) + (ps2 + ps3);
    psum += __shfl_xor(psum, 32);

    __syncthreads();   // staging buffers dead; reuse as exchange region
    float* ep = (float*)lds + qhalf * (64 * 36);   // per-q-half region, 9216 B
    float* slot = ep + lane * 36;
    if (par == 1) {
#pragma unroll
        for (int dblk = 0; dblk < 2; ++dblk)
#pragma unroll
            for (int g2 = 0; g2 < 4; ++g2)
                *(float4*)(slot + dblk * 16 + g2 * 4) =
                    (float4){oacc[dblk][4*g2+0], oacc[dblk][4*g2+1],
                             oacc[dblk][4*g2+2], oacc[dblk][4*g2+3]};
        slot[32] = psum;
    }
    __syncthreads();
    if (par == 0) {
#pragma unroll
        for (int dblk = 0; dblk < 2; ++dblk)
#pragma unroll
            for (int g2 = 0; g2 < 4; ++g2) {
                float4 o = *(const float4*)(slot + dblk * 16 + g2 * 4);
                oacc[dblk][4*g2+0] += o.x; oacc[dblk][4*g2+1] += o.y;
                oacc[dblk][4*g2+2] += o.z; oacc[dblk][4*g2+3] += o.w;
            }
        psum += slot[32];

        const float inv = 1.f / psum;
#pragma unroll
        for (int dblk = 0; dblk < 2; ++dblk)
#pragma unroll
            for (int g2 = 0; g2 < 4; ++g2) {
                float4 o = {oacc[dblk][4*g2+0] * inv, oacc[dblk][4*g2+1] * inv,
                            oacc[dblk][4*g2+2] * inv, oacc[dblk][4*g2+3] * inv};
                *(float4*)(Op + (size_t)qrow * DH + dblk * 32 + g2 * 8 + hi * 4) = o;
            }
    }
}

extern "C" void kernel_launch(void* const* d_in, const int* in_sizes, int n_in,
                              void* d_out, int out_size, void* d_ws, size_t ws_size,
                              hipStream_t stream) {
    const float* q = (const float*)d_in[0];
    const float* k = (const float*)d_in[1];
    const float* v = (const float*)d_in[2];
    float* out = (float*)d_out;
    const int BH = in_sizes[0] / (SQ * DH);   // 32
    bf16* Kb  = (bf16*)d_ws;
    bf16* Vtb = (bf16*)((char*)d_ws + (size_t)BH * SQ * DH * sizeof(bf16));
    alibi_prep_kernel<<<dim3(SQ / 64, BH, 2), dim3(256), 0, stream>>>(k, v, Kb, Vtb);
    const int nblk = BH * (SQ / QBLK);        // 1024 work items (q-block, bh)
    alibi_attn_kernel<<<dim3(nblk), dim3(256), 0, stream>>>(q, Kb, Vtb, out);
}